// Round 9
// baseline (268.008 us; speedup 1.0000x reference)
//
#include <hip/hip_runtime.h>
#include <cstdint>

// Problem constants (from reference setup_inputs)
#define BATCH   16
#define CCH     512
#define DD      32
#define NCODES  16384
#define HWSZ    1024            // 32*32
#define P_TOTAL 16384           // BATCH * HWSZ
#define NCHUNK  16
#define CHUNK   (NCODES / NCHUNK)   // 1024 codes per chunk

typedef _Float16 half8 __attribute__((ext_vector_type(8)));
typedef float    f32x4 __attribute__((ext_vector_type(4)));

union H8 { _Float16 h[8]; uint4 u; };
union L8 { uint4 u; half8 h; };

// f16 split row layout: row = 128 B = [32 f16 hi | 32 f16 lo], values scaled
// by 2^12 so lo-terms stay in f16 normal range. sim accumulates at scale
// 2^24; argmax is scale-invariant. 4 exact product terms -> ~2^-22 rel err.

// ---------------------------------------------------------------------------
// Kernel PREP (fused): grid 384 blocks x 256 thr.
//   blocks [0,256):  proj  z[p][d] = sum_c enc*pw + pb, invz, zf16 split rows
//   blocks [256,320): enorm en rows + ef16 split rows
//   blocks [320,384): zero hist + scalarAcc
// ---------------------------------------------------------------------------
__global__ __launch_bounds__(256) void prep_kernel(
    const float* __restrict__ enc, const float* __restrict__ pw,
    const float* __restrict__ pb, const float* __restrict__ emb,
    float* __restrict__ z, float* __restrict__ invz, char* __restrict__ zf16,
    float* __restrict__ en, char* __restrict__ ef16,
    int* __restrict__ hist, float* __restrict__ scalarAcc)
{
    const int t = threadIdx.x;

    if (blockIdx.x >= 320) {                 // ---- hist/scalar zeroing ----
        const int i = (blockIdx.x - 320) * 256 + t;
        hist[i] = 0;
        if (blockIdx.x == 320 && t < 4) scalarAcc[t] = 0.f;
        return;
    }

    if (blockIdx.x >= 256) {                 // ---- enorm ----
        const int r = (blockIdx.x - 256) * 256 + t;
        const float4* src = reinterpret_cast<const float4*>(emb + (size_t)r * DD);
        float4 v[8];
        float ssq = 0.f;
#pragma unroll
        for (int q = 0; q < 8; q++) {
            v[q] = src[q];
            ssq += v[q].x * v[q].x + v[q].y * v[q].y + v[q].z * v[q].z + v[q].w * v[q].w;
        }
        const float inv = 1.f / fmaxf(sqrtf(ssq), 1e-6f);
        float4* dst = reinterpret_cast<float4*>(en + (size_t)r * DD);
        char* row = ef16 + (size_t)r * 128;
#pragma unroll
        for (int q = 0; q < 8; q += 2) {
            H8 hi, lo;
#pragma unroll
            for (int u = 0; u < 2; u++) {
                float4 o;
                o.x = v[q + u].x * inv; o.y = v[q + u].y * inv;
                o.z = v[q + u].z * inv; o.w = v[q + u].w * inv;
                dst[q + u] = o;
                const float s[4] = {o.x * 4096.f, o.y * 4096.f, o.z * 4096.f, o.w * 4096.f};
#pragma unroll
                for (int j = 0; j < 4; j++) {
                    const _Float16 h = (_Float16)s[j];
                    hi.h[u * 4 + j] = h;
                    lo.h[u * 4 + j] = (_Float16)(s[j] - (float)h);
                }
            }
            *(uint4*)(row + q * 8)      = hi.u;
            *(uint4*)(row + 64 + q * 8) = lo.u;
        }
        return;
    }

    // ---- proj ----
    const int hw_l = t & 63;
    const int dg   = __builtin_amdgcn_readfirstlane(t >> 6);   // SGPR-uniform
    const int p0   = blockIdx.x * 64;
    const int b    = p0 >> 10;
    const int hw   = (p0 & 1023) + hw_l;
    const float* encb = enc + (size_t)b * (CCH * HWSZ) + hw;

    float acc[8];
#pragma unroll
    for (int j = 0; j < 8; j++) acc[j] = 0.f;

    float ev[16];
#pragma unroll
    for (int u = 0; u < 16; u++) ev[u] = encb[(size_t)u * HWSZ];

    for (int c0 = 0; c0 < CCH - 16; c0 += 16) {
        float nv[16];
#pragma unroll
        for (int u = 0; u < 16; u++)             // next batch in flight
            nv[u] = encb[(size_t)(c0 + 16 + u) * HWSZ];
#pragma unroll
        for (int u = 0; u < 16; u++)
#pragma unroll
            for (int j = 0; j < 8; j++)          // uniform -> s_load
                acc[j] = fmaf(ev[u], pw[(dg * 8 + j) * CCH + c0 + u], acc[j]);
#pragma unroll
        for (int u = 0; u < 16; u++) ev[u] = nv[u];
    }
#pragma unroll
    for (int u = 0; u < 16; u++)                 // final batch
#pragma unroll
        for (int j = 0; j < 8; j++)
            acc[j] = fmaf(ev[u], pw[(dg * 8 + j) * CCH + (CCH - 16) + u], acc[j]);

    const int p = p0 + hw_l;
    float ssq = 0.f;
    H8 hi, lo;
#pragma unroll
    for (int j = 0; j < 8; j++) {
        const float v = acc[j] + pb[dg * 8 + j];
        z[(size_t)p * DD + dg * 8 + j] = v;
        ssq = fmaf(v, v, ssq);
        const float vs = v * 4096.f;
        const _Float16 h = (_Float16)vs;
        hi.h[j] = h;
        lo.h[j] = (_Float16)(vs - (float)h);
    }
    char* row = zf16 + (size_t)p * 128;
    *(uint4*)(row + dg * 16)      = hi.u;
    *(uint4*)(row + 64 + dg * 16) = lo.u;

    __shared__ float red[4][64];
    red[dg][hw_l] = ssq;
    __syncthreads();
    if (t < 64) {
        const float tot = red[0][t] + red[1][t] + red[2][t] + red[3][t];
        invz[p0 + t] = 1.f / fmaxf(sqrtf(tot), 1e-6f);
    }
}

// ---------------------------------------------------------------------------
// Kernel C: fused MFMA sims + argmax over one 1024-code chunk.
// R8 = R7 ILP structure (rounds of 4 tiles: next round's 8 A-fragments
// prefetched across the round's 64 MFMAs; 16 INDEPENDENT depth-4 chains
// emitted step-major so the matrix pipe fills regardless of chain latency)
// with the EXACT per-element epilogue restored (cmp + 2 cndmask per sim).
// R7's recover-by-recompute was invalid: MFMA is wave-collective, per-lane
// btile made the recompute's A matrix a cross-lane mix -> garbage indices.
// D layout: code=(lane>>4)*4+reg, pos=lane&15; per-lane scan ascending
// (tiles, then r) with strict > = first occurrence; shfl_xor(16,32) reduce
// with equal->lower-code tie-break == numpy argmax semantics.
// ---------------------------------------------------------------------------
__global__ __launch_bounds__(256) void argmax_kernel(
    const char* __restrict__ zf16, const char* __restrict__ ef16,
    float* __restrict__ pval, int* __restrict__ pidx)
{
    const int w    = threadIdx.x >> 6;       // wave 0..3
    const int lane = threadIdx.x & 63;
    const int col  = lane & 15;
    const int quad = lane >> 4;
    const int pg    = blockIdx.x & 63;       // 64 position groups of 256
    const int chunk = blockIdx.x >> 6;       // 16 chunks of 1024 codes
    const int wp0   = pg * 256 + w * 64;     // wave position base (64 pos)

    // B fragments (z): pos-tile tt rows wp0 + tt*16 + col
    half8 bh[4], bl[4];
#pragma unroll
    for (int tt = 0; tt < 4; tt++) {
        const char* r = zf16 + (size_t)(wp0 + tt * 16 + col) * 128 + quad * 16;
        L8 a; a.u = *(const uint4*)(r);       bh[tt] = a.h;
        L8 b; b.u = *(const uint4*)(r + 64);  bl[tt] = b.h;
    }

    const int n0 = chunk * CHUNK;
    const char* abase = ef16 + (size_t)(n0 + col) * 128 + quad * 16;

    float best[4]  = {-3e38f, -3e38f, -3e38f, -3e38f};
    int   bcode[4] = {0, 0, 0, 0};
    const f32x4 zero4 = {0.f, 0.f, 0.f, 0.f};

    // current-round A regs (4 tiles x hi/lo)
    uint4 cah[4], cal[4];
#pragma unroll
    for (int it = 0; it < 4; it++) {
        cah[it] = *(const uint4*)(abase + it * 2048);
        cal[it] = *(const uint4*)(abase + it * 2048 + 64);
    }

    for (int rnd = 0; rnd < CHUNK / 64; rnd++) {
        // prefetch next round's 8 fragments (over-reads ~8KB past chunk end
        // on the last round: lands in the pval region — allocated, safe)
        const char* nb = abase + (size_t)(rnd + 1) * 8192;
        uint4 nah[4], nal[4];
#pragma unroll
        for (int it = 0; it < 4; it++) {
            nah[it] = *(const uint4*)(nb + it * 2048);
            nal[it] = *(const uint4*)(nb + it * 2048 + 64);
        }

        half8 ah[4], al[4];
#pragma unroll
        for (int it = 0; it < 4; it++) {
            L8 x; x.u = cah[it]; ah[it] = x.h;
            L8 y; y.u = cal[it]; al[it] = y.h;
        }

        // 16 independent depth-4 chains, emitted step-major
        f32x4 acc[4][4];
#pragma unroll
        for (int it = 0; it < 4; it++)
#pragma unroll
            for (int tt = 0; tt < 4; tt++)
                acc[it][tt] = __builtin_amdgcn_mfma_f32_16x16x32_f16(ah[it], bh[tt], zero4, 0, 0, 0);
#pragma unroll
        for (int it = 0; it < 4; it++)
#pragma unroll
            for (int tt = 0; tt < 4; tt++)
                acc[it][tt] = __builtin_amdgcn_mfma_f32_16x16x32_f16(ah[it], bl[tt], acc[it][tt], 0, 0, 0);
#pragma unroll
        for (int it = 0; it < 4; it++)
#pragma unroll
            for (int tt = 0; tt < 4; tt++)
                acc[it][tt] = __builtin_amdgcn_mfma_f32_16x16x32_f16(al[it], bh[tt], acc[it][tt], 0, 0, 0);
#pragma unroll
        for (int it = 0; it < 4; it++)
#pragma unroll
            for (int tt = 0; tt < 4; tt++)
                acc[it][tt] = __builtin_amdgcn_mfma_f32_16x16x32_f16(al[it], bl[tt], acc[it][tt], 0, 0, 0);

        // exact per-element epilogue: strict > ascending == first occurrence
#pragma unroll
        for (int it = 0; it < 4; it++) {
            const int base = n0 + (rnd * 4 + it) * 16 + quad * 4;
#pragma unroll
            for (int tt = 0; tt < 4; tt++) {
                const f32x4 a = acc[it][tt];
#pragma unroll
                for (int r = 0; r < 4; r++) {
                    if (a[r] > best[tt]) { best[tt] = a[r]; bcode[tt] = base + r; }
                }
            }
        }

#pragma unroll
        for (int it = 0; it < 4; it++) { cah[it] = nah[it]; cal[it] = nal[it]; }
    }

    // reduce across the 4 quads holding the same position (xor 16, 32)
#pragma unroll
    for (int off = 16; off < 64; off <<= 1) {
#pragma unroll
        for (int tt = 0; tt < 4; tt++) {
            const float ov = __shfl_xor(best[tt], off);
            const int   oi = __shfl_xor(bcode[tt], off);
            if (ov > best[tt] || (ov == best[tt] && oi < bcode[tt])) {
                best[tt] = ov; bcode[tt] = oi;
            }
        }
    }
    if (quad == 0) {
#pragma unroll
        for (int tt = 0; tt < 4; tt++) {
            pval[(size_t)chunk * P_TOTAL + wp0 + tt * 16 + col] = best[tt];
            pidx[(size_t)chunk * P_TOTAL + wp0 + tt * 16 + col] = bcode[tt];
        }
    }
}

// ---------------------------------------------------------------------------
// Kernel COMBEX (fused combine + expand): 256 blocks x 512 thr, 64 pos each.
// Phase 1 (all 8 waves): per-position partial argmax over 2 chunks/kgroup.
// Phase 2 (wave 0): finalize argmax (idx tie-break = lowest code), hist
// atomic, quantization-loss (shfl-reduced), stage en[idx] rows into LDS.
// Phase 3 (all): out[b][c][hw] = lat . exp_w[c] + exp_b[c]; ew via s_load.
// ---------------------------------------------------------------------------
__global__ __launch_bounds__(512) void combex_kernel(
    const float* __restrict__ pval, const int* __restrict__ pidx,
    const float* __restrict__ z, const float* __restrict__ invz,
    const float* __restrict__ en, const float* __restrict__ ew,
    const float* __restrict__ eb,
    int* __restrict__ hist, float* __restrict__ scalarAcc,
    float* __restrict__ out)
{
    const int t  = threadIdx.x;
    const int p0 = blockIdx.x * 64;

    __shared__ float lat[64 * 33];
    __shared__ float bvs[8][64];
    __shared__ int   bis[8][64];

    {   // phase 1: 8 kgroups x 2 chunks, ascending k (strict > = lowest k)
        const int pl = t & 63;
        const int kg = t >> 6;
        const int p  = p0 + pl;
        float best = -3e38f;
        int   bi   = 0;
#pragma unroll
        for (int k = 0; k < 2; k++) {
            const float v = pval[(size_t)(kg * 2 + k) * P_TOTAL + p];
            const int   i = pidx[(size_t)(kg * 2 + k) * P_TOTAL + p];
            if (v > best) { best = v; bi = i; }
        }
        bvs[kg][pl] = best;
        bis[kg][pl] = bi;
    }
    __syncthreads();

    if (t < 64) {   // phase 2 (wave 0)
        float best = bvs[0][t];
        int   bi   = bis[0][t];
#pragma unroll
        for (int kg = 1; kg < 8; kg++) {
            const float v = bvs[kg][t];
            const int   i = bis[kg][t];
            if (v > best || (v == best && i < bi)) { best = v; bi = i; }
        }
        const int p = p0 + t;
        atomicAdd(&hist[bi], 1);

        const float iv = invz[p];
        const float4* zsrc = reinterpret_cast<const float4*>(z + (size_t)p * DD);
        const float4* esrc = reinterpret_cast<const float4*>(en + (size_t)bi * DD);
        float ls = 0.f;
#pragma unroll
        for (int q = 0; q < 8; q++) {
            const float4 zv = zsrc[q];
            const float4 ev = esrc[q];
            lat[t * 33 + q * 4 + 0] = ev.x;
            lat[t * 33 + q * 4 + 1] = ev.y;
            lat[t * 33 + q * 4 + 2] = ev.z;
            lat[t * 33 + q * 4 + 3] = ev.w;
            const float dx = zv.x * iv - ev.x;
            const float dy = zv.y * iv - ev.y;
            const float dz = zv.z * iv - ev.z;
            const float dw = zv.w * iv - ev.w;
            ls += dx * dx + dy * dy + dz * dz + dw * dw;
        }
#pragma unroll
        for (int off = 32; off > 0; off >>= 1) ls += __shfl_down(ls, off);
        if (t == 0) atomicAdd(&scalarAcc[0], ls);
    }
    __syncthreads();

    // phase 3: expand — 8 waves x 64 c each
    const int hw_l = t & 63;
    const int cg   = __builtin_amdgcn_readfirstlane(t >> 6);   // 0..7
    float lr[32];
#pragma unroll
    for (int d = 0; d < DD; d++) lr[d] = lat[hw_l * 33 + d];

    const int b   = p0 >> 10;
    const int hw0 = p0 & 1023;
    float* outb = out + (size_t)b * (CCH * HWSZ) + hw0 + hw_l;
    const int c0 = cg * 64;
#pragma unroll 4
    for (int k = 0; k < 64; k++) {
        const int c = c0 + k;
        const float* ewc = ew + (size_t)c * DD;      // uniform -> s_load
        float s0 = 0.f, s1 = 0.f, s2 = 0.f, s3 = 0.f;
#pragma unroll
        for (int d = 0; d < DD; d += 4) {
            s0 = fmaf(lr[d + 0], ewc[d + 0], s0);
            s1 = fmaf(lr[d + 1], ewc[d + 1], s1);
            s2 = fmaf(lr[d + 2], ewc[d + 2], s2);
            s3 = fmaf(lr[d + 3], ewc[d + 3], s3);
        }
        outb[(size_t)c * HWSZ] = (s0 + s1) + (s2 + s3) + eb[c];
    }
}

// ---------------------------------------------------------------------------
// Kernel ENTROPY: 64 blocks x 256 thr, one hist element each. Last block
// (device-scope done-counter) finalizes both scalar outputs.
// ---------------------------------------------------------------------------
__global__ __launch_bounds__(256) void entropy_kernel(
    const int* __restrict__ hist, float* __restrict__ scalarAcc,
    float* __restrict__ out_scalars)
{
    const int i = blockIdx.x * 256 + threadIdx.x;
    const float u = (float)hist[i] * (1.f / (float)P_TOTAL);
    float h = -u * logf(u + 1e-6f);
    __shared__ float red[256];
    red[threadIdx.x] = h;
    __syncthreads();
    for (int s = 128; s > 0; s >>= 1) {
        if (threadIdx.x < s) red[threadIdx.x] += red[threadIdx.x + s];
        __syncthreads();
    }
    if (threadIdx.x == 0) {
        atomicAdd(&scalarAcc[1], red[0]);
        __threadfence();
        int* cnt = (int*)(scalarAcc + 2);
        const int prev = atomicAdd(cnt, 1);
        if (prev == 63) {    // last block: all adds are visible
            const float loss = __hip_atomic_load(&scalarAcc[0], __ATOMIC_RELAXED,
                                                 __HIP_MEMORY_SCOPE_AGENT);
            const float ent  = __hip_atomic_load(&scalarAcc[1], __ATOMIC_RELAXED,
                                                 __HIP_MEMORY_SCOPE_AGENT);
            out_scalars[0] = loss * (1.f / (float)(P_TOTAL * DD));
            out_scalars[1] = expf(ent);
        }
    }
}

// ---------------------------------------------------------------------------
// Workspace layout (bytes):
//   z      @ 0        : 16384*32*4  = 2,097,152
//   invz   @ 2097152  : 16384*4     =    65,536
//   en     @ 2162688  : 16384*32*4  = 2,097,152
//   zf16   @ 4259840  : 16384*128   = 2,097,152  (hi|lo f16 rows, x4096)
//   ef16   @ 6356992  : 16384*128   = 2,097,152
//   pval   @ 8454144  : 16*16384*4  = 1,048,576  (also argmax over-read pad)
//   pidx   @ 9502720  : 16*16384*4  = 1,048,576
//   hist   @ 10551296 : 16384*4     =    65,536
//   scalarAcc @ 10616832 : 4*4  (loss, entropy, done-counter, pad)
//   total ~10.6 MB
// ---------------------------------------------------------------------------
extern "C" void kernel_launch(void* const* d_in, const int* in_sizes, int n_in,
                              void* d_out, int out_size, void* d_ws, size_t ws_size,
                              hipStream_t stream)
{
    const float* enc = (const float*)d_in[0];   // [16,512,32,32]
    const float* emb = (const float*)d_in[1];   // [16384,32]
    const float* pw  = (const float*)d_in[2];   // [32,512]
    const float* pb  = (const float*)d_in[3];   // [32]
    const float* ew  = (const float*)d_in[4];   // [512,32]
    const float* eb  = (const float*)d_in[5];   // [512]
    float* out = (float*)d_out;                 // 8388608 + loss + perplexity

    char* ws = (char*)d_ws;
    float* z         = (float*)(ws + 0);
    float* invz      = (float*)(ws + 2097152);
    float* en        = (float*)(ws + 2162688);
    char*  zf16      = ws + 4259840;
    char*  ef16      = ws + 6356992;
    float* pval      = (float*)(ws + 8454144);
    int*   pidx      = (int*)  (ws + 9502720);
    int*   hist      = (int*)  (ws + 10551296);
    float* scalarAcc = (float*)(ws + 10616832);

    prep_kernel   <<<384, 256, 0, stream>>>(enc, pw, pb, emb, z, invz, zf16,
                                            en, ef16, hist, scalarAcc);
    argmax_kernel <<<64 * NCHUNK, 256, 0, stream>>>(zf16, ef16, pval, pidx);
    combex_kernel <<<P_TOTAL / 64, 512, 0, stream>>>(pval, pidx, z, invz, en,
                                                     ew, eb, hist, scalarAcc, out);
    entropy_kernel<<<NCODES / 256, 256, 0, stream>>>(hist, scalarAcc,
                                                     out + 8388608);
}